// Round 1
// baseline (12762.277 us; speedup 1.0000x reference)
//
#include <hip/hip_runtime.h>

namespace {
constexpr int kB  = 16;
constexpr int kC  = 512;
constexpr int kC2 = 256;
constexpr int kN  = 2304;   // 48*48

constexpr int BM = 128, BN = 128, BK = 16;
}

// ---------------------------------------------------------------------------
// Generic fp32 tiled GEMM: C = A*B (+bias / gamma*acc+aux epilogues)
//   TRANS_A=false: A is M x K row-major (lda = K-stride)
//   TRANS_A=true : A is K x M row-major (lda = M-stride)  [reduction over rows]
//   B is K x N row-major. Grid covers exact tiles (no bounds checks; all dims
//   divide 128/16 for this problem).
//   EPI: 0 = none, 1 = +bias[m], 2 = gamma*acc + aux[m,n]
// ---------------------------------------------------------------------------

#define LOAD_TILE(k0)                                                          \
  {                                                                            \
    if constexpr (TRANS_A) {                                                   \
      ra0 = *(const float4*)&A[(long)((k0) + (tid >> 5)) * lda + m0 +          \
                               ((tid & 31) << 2)];                             \
      ra1 = *(const float4*)&A[(long)((k0) + (tid >> 5) + 8) * lda + m0 +      \
                               ((tid & 31) << 2)];                             \
    } else {                                                                   \
      ra0 = *(const float4*)&A[(long)(m0 + (tid >> 2)) * lda + (k0) +          \
                               ((tid & 3) << 2)];                              \
      ra1 = *(const float4*)&A[(long)(m0 + (tid >> 2) + 64) * lda + (k0) +     \
                               ((tid & 3) << 2)];                              \
    }                                                                          \
    rb0 = *(const float4*)&B[(long)((k0) + (tid >> 5)) * ldb + n0 +            \
                             ((tid & 31) << 2)];                               \
    rb1 = *(const float4*)&B[(long)((k0) + (tid >> 5) + 8) * ldb + n0 +        \
                             ((tid & 31) << 2)];                               \
  }

#define STORE_TILE(buf)                                                        \
  {                                                                            \
    if constexpr (TRANS_A) {                                                   \
      *(float4*)&As[buf][tid >> 5][(tid & 31) << 2] = ra0;                     \
      *(float4*)&As[buf][(tid >> 5) + 8][(tid & 31) << 2] = ra1;               \
    } else {                                                                   \
      const int mm = tid >> 2, k4 = (tid & 3) << 2;                            \
      As[buf][k4 + 0][mm] = ra0.x; As[buf][k4 + 1][mm] = ra0.y;                \
      As[buf][k4 + 2][mm] = ra0.z; As[buf][k4 + 3][mm] = ra0.w;                \
      As[buf][k4 + 0][mm + 64] = ra1.x; As[buf][k4 + 1][mm + 64] = ra1.y;      \
      As[buf][k4 + 2][mm + 64] = ra1.z; As[buf][k4 + 3][mm + 64] = ra1.w;      \
    }                                                                          \
    *(float4*)&Bs[buf][tid >> 5][(tid & 31) << 2] = rb0;                       \
    *(float4*)&Bs[buf][(tid >> 5) + 8][(tid & 31) << 2] = rb1;                 \
  }

template <bool TRANS_A, int EPI>
__global__ __launch_bounds__(256, 2) void gemm_f32(
    const float* __restrict__ A, long sA, int lda,
    const float* __restrict__ B, long sB, int ldb,
    float* __restrict__ C, long sC, int ldc,
    const float* __restrict__ bias,
    const float* __restrict__ aux, long sAux, int ldaux,
    const float* __restrict__ gammap, int K)
{
  const int bz = blockIdx.z;
  A += (long)bz * sA;
  B += (long)bz * sB;
  C += (long)bz * sC;
  if constexpr (EPI == 2) aux += (long)bz * sAux;

  __shared__ float As[2][BK][BM + 4];
  __shared__ float Bs[2][BK][BN + 4];

  const int tid = threadIdx.x;
  const int tn = tid & 15;
  const int tm = tid >> 4;
  const int m0 = blockIdx.y * BM;
  const int n0 = blockIdx.x * BN;

  float acc[2][2][4][4];
#pragma unroll
  for (int a = 0; a < 2; ++a)
#pragma unroll
    for (int b = 0; b < 2; ++b)
#pragma unroll
      for (int i = 0; i < 4; ++i)
#pragma unroll
        for (int j = 0; j < 4; ++j) acc[a][b][i][j] = 0.f;

  float4 ra0, ra1, rb0, rb1;

  const int nT = K / BK;
  LOAD_TILE(0);
  STORE_TILE(0);
  __syncthreads();

  for (int t = 0; t < nT; ++t) {
    const int cur = t & 1;
    if (t + 1 < nT) LOAD_TILE((t + 1) * BK);

#pragma unroll
    for (int kk = 0; kk < BK; ++kk) {
      float av[2][4], bv[2][4];
      *(float4*)&av[0][0] = *(const float4*)&As[cur][kk][tm * 4];
      *(float4*)&av[1][0] = *(const float4*)&As[cur][kk][64 + tm * 4];
      *(float4*)&bv[0][0] = *(const float4*)&Bs[cur][kk][tn * 4];
      *(float4*)&bv[1][0] = *(const float4*)&Bs[cur][kk][64 + tn * 4];
#pragma unroll
      for (int a = 0; a < 2; ++a)
#pragma unroll
        for (int i = 0; i < 4; ++i)
#pragma unroll
          for (int b = 0; b < 2; ++b)
#pragma unroll
            for (int j = 0; j < 4; ++j)
              acc[a][b][i][j] = fmaf(av[a][i], bv[b][j], acc[a][b][i][j]);
    }

    if (t + 1 < nT) STORE_TILE(cur ^ 1);
    __syncthreads();
  }

  float gma = 0.f;
  if constexpr (EPI == 2) gma = *gammap;

#pragma unroll
  for (int a = 0; a < 2; ++a) {
#pragma unroll
    for (int i = 0; i < 4; ++i) {
      const int m = m0 + a * 64 + tm * 4 + i;
      float bv_ = 0.f;
      if constexpr (EPI == 1) bv_ = bias[m];
#pragma unroll
      for (int b = 0; b < 2; ++b) {
        const int n = n0 + b * 64 + tn * 4;
        float4 v = make_float4(acc[a][b][i][0], acc[a][b][i][1],
                               acc[a][b][i][2], acc[a][b][i][3]);
        if constexpr (EPI == 1) {
          v.x += bv_; v.y += bv_; v.z += bv_; v.w += bv_;
        }
        if constexpr (EPI == 2) {
          const float4 wv = *(const float4*)&aux[(long)m * ldaux + n];
          v.x = gma * v.x + wv.x; v.y = gma * v.y + wv.y;
          v.z = gma * v.z + wv.z; v.w = gma * v.w + wv.w;
        }
        *(float4*)&C[(long)m * ldc + n] = v;
      }
    }
  }
}

// ---------------------------------------------------------------------------
// In-place row softmax, row length 2304 (= 9 * 256). One 256-thread block/row.
// ---------------------------------------------------------------------------
__global__ __launch_bounds__(256) void softmax_rows_2304(float* __restrict__ P)
{
  float* p = P + (long)blockIdx.x * kN;
  const int tid = threadIdx.x;

  float v[9];
  float mx = -3.402823466e38f;
#pragma unroll
  for (int r = 0; r < 9; ++r) {
    v[r] = p[tid + 256 * r];
    mx = fmaxf(mx, v[r]);
  }
#pragma unroll
  for (int off = 32; off > 0; off >>= 1) mx = fmaxf(mx, __shfl_xor(mx, off, 64));

  __shared__ float red[8];
  const int wv = tid >> 6, ln = tid & 63;
  if (ln == 0) red[wv] = mx;
  __syncthreads();
  mx = fmaxf(fmaxf(red[0], red[1]), fmaxf(red[2], red[3]));

  float s = 0.f;
#pragma unroll
  for (int r = 0; r < 9; ++r) {
    v[r] = __expf(v[r] - mx);
    s += v[r];
  }
#pragma unroll
  for (int off = 32; off > 0; off >>= 1) s += __shfl_xor(s, off, 64);
  if (ln == 0) red[4 + wv] = s;
  __syncthreads();
  s = red[4] + red[5] + red[6] + red[7];

  const float inv = 1.f / s;
#pragma unroll
  for (int r = 0; r < 9; ++r) p[tid + 256 * r] = v[r] * inv;
}

// ---------------------------------------------------------------------------
extern "C" void kernel_launch(void* const* d_in, const int* in_sizes, int n_in,
                              void* d_out, int out_size, void* d_ws,
                              size_t ws_size, hipStream_t stream)
{
  const float* x  = (const float*)d_in[0];
  const float* w  = (const float*)d_in[1];
  const float* Wf = (const float*)d_in[2];
  const float* bf = (const float*)d_in[3];
  const float* Wg = (const float*)d_in[4];
  const float* bg = (const float*)d_in[5];
  const float* Wh = (const float*)d_in[6];
  const float* bh = (const float*)d_in[7];
  const float* gm = (const float*)d_in[8];

  float* f_w = (float*)d_ws;                      // [B][C2][N]
  float* g_x = f_w + (long)kB * kC2 * kN;         // [B][C2][N]
  float* h_x = g_x + (long)kB * kC2 * kN;         // [B][C ][N]

  float* out1 = (float*)d_out;                    // [B][C][N]  (self_attn_map)
  float* out2 = out1 + (long)kB * kC * kN;        // [B][N][N]  (attn_soft^T)

  dim3 blk(256);

  // f_w = Wf @ w + bf   (per batch: 256 x 2304 x 512)
  gemm_f32<false, 1><<<dim3(kN / BN, kC2 / BM, kB), blk, 0, stream>>>(
      Wf, 0, kC, w, (long)kC * kN, kN, f_w, (long)kC2 * kN, kN, bf,
      nullptr, 0, 0, nullptr, kC);
  // g_x = Wg @ x + bg
  gemm_f32<false, 1><<<dim3(kN / BN, kC2 / BM, kB), blk, 0, stream>>>(
      Wg, 0, kC, x, (long)kC * kN, kN, g_x, (long)kC2 * kN, kN, bg,
      nullptr, 0, 0, nullptr, kC);
  // h_x = Wh @ x + bh   (512 x 2304 x 512)
  gemm_f32<false, 1><<<dim3(kN / BN, kC / BM, kB), blk, 0, stream>>>(
      Wh, 0, kC, x, (long)kC * kN, kN, h_x, (long)kC * kN, kN, bh,
      nullptr, 0, 0, nullptr, kC);
  // out2[b,j,i] = sum_c g_x[b,c,j] * f_w[b,c,i]   (transposed logits, 2304x2304x256)
  gemm_f32<true, 0><<<dim3(kN / BN, kN / BM, kB), blk, 0, stream>>>(
      g_x, (long)kC2 * kN, kN, f_w, (long)kC2 * kN, kN, out2, (long)kN * kN, kN,
      nullptr, nullptr, 0, 0, nullptr, kC2);
  // softmax over i == contiguous rows of out2
  softmax_rows_2304<<<dim3(kB * kN), blk, 0, stream>>>(out2);
  // out1 = gamma * (h_x @ out2) + w   (512 x 2304 x 2304)
  gemm_f32<false, 2><<<dim3(kN / BN, kC / BM, kB), blk, 0, stream>>>(
      h_x, (long)kC * kN, kN, out2, (long)kN * kN, kN, out1, (long)kC * kN, kN,
      nullptr, w, (long)kC * kN, kN, gm, kN);
}

// Round 2
// 1372.185 us; speedup vs baseline: 9.3007x; 9.3007x over previous
//
#include <hip/hip_runtime.h>

typedef unsigned short u16;
typedef unsigned int u32;
typedef __attribute__((ext_vector_type(8))) short bf16x8;
typedef __attribute__((ext_vector_type(4))) float f32x4;

namespace {
constexpr int kB = 16, kC = 512, kC2 = 256, kN = 2304;
}

// ---- fp32 -> (hi, lo) bf16 split (round-to-nearest-even-ish via RN bias) ----
__device__ __forceinline__ u16 bf16rn(float v) {
  u32 u = __float_as_uint(v);
  return (u16)((u + 0x7FFFu + ((u >> 16) & 1u)) >> 16);
}
__device__ __forceinline__ void splitbf(float v, u16& h, u16& l) {
  u16 hb = bf16rn(v);
  float hv = __uint_as_float(((u32)hb) << 16);
  h = hb;
  l = bf16rn(v - hv);
}

typedef const __attribute__((address_space(1))) void* gas_t;
typedef __attribute__((address_space(3))) void* las_t;
__device__ __forceinline__ void gload16(const void* g, void* l) {
  __builtin_amdgcn_global_load_lds((gas_t)g, (las_t)l, 16, 0, 0);
}

// ===========================================================================
// conv_gemm: C_planes = split( A * B^T-ish + bias ) with on-the-fly fp32->bf16
//   "T" operand: source [K][cols] fp32 (channels-major), transpose-staged.
//   "D" operand: source [rows][K] fp32 (K-contiguous), direct-staged.
//   TRANS_A=true : T feeds M side (G1/G2: spatial rows), D feeds N side.
//   TRANS_A=false: D feeds M side (G3: Wh rows), T feeds N side.
//   Output: two bf16 planes [M][ldc], value = acc + bias (col- or row-indexed).
//   3-term split-bf16 MFMA, BM=BN=128, BK=64, XOR-swizzled LDS (both sides).
// ===========================================================================
template <bool TRANS_A, bool BIAS_COL>
__global__ __launch_bounds__(256, 2) void conv_gemm(
    const float* __restrict__ Tsrc, int ldT, long sT,
    const float* __restrict__ Dsrc, int ldD, long sD,
    u16* __restrict__ Chi, u16* __restrict__ Clo, int ldc, long sC,
    const float* __restrict__ bias, int K)
{
  __shared__ u16 Ah[128][64], Al[128][64], Bh[128][64], Bl[128][64];

  const int tid = threadIdx.x, ln = tid & 63, wv = tid >> 6;
  const int z = blockIdx.z;
  const int m0 = blockIdx.y * 128, n0 = blockIdx.x * 128;

  const float* T = Tsrc + (long)z * sT + (TRANS_A ? m0 : n0);
  const float* D = Dsrc + (long)z * sD + (long)(TRANS_A ? n0 : m0) * ldD;
  u16* Co_h = Chi + (long)z * sC;
  u16* Co_l = Clo + (long)z * sC;

  u16 (*Tph)[64] = TRANS_A ? Ah : Bh;
  u16 (*Tpl)[64] = TRANS_A ? Al : Bl;
  u16 (*Dph)[64] = TRANS_A ? Bh : Ah;
  u16 (*Dpl)[64] = TRANS_A ? Bl : Al;

  auto stage = [&](int k0) {
    // transposed operand: coalesced-across-lanes strided scalar loads,
    // pack 8 k-elems -> one b128 write per plane, slot-swizzled.
#pragma unroll
    for (int s = 0; s < 4; ++s) {
      const int m = (tid & 63) + 64 * (s & 1);
      const int kr = (tid >> 6) + 4 * (s >> 1);
      const float* src = T + (long)(k0 + kr * 8) * ldT + m;
      u16 h[8], l[8];
#pragma unroll
      for (int j = 0; j < 8; ++j) splitbf(src[(long)j * ldT], h[j], l[j]);
      uint4 ph, pl;
      ph.x = (u32)h[0] | ((u32)h[1] << 16); ph.y = (u32)h[2] | ((u32)h[3] << 16);
      ph.z = (u32)h[4] | ((u32)h[5] << 16); ph.w = (u32)h[6] | ((u32)h[7] << 16);
      pl.x = (u32)l[0] | ((u32)l[1] << 16); pl.y = (u32)l[2] | ((u32)l[3] << 16);
      pl.z = (u32)l[4] | ((u32)l[5] << 16); pl.w = (u32)l[6] | ((u32)l[7] << 16);
      const int sw = (kr ^ (m & 7)) * 8;
      *(uint4*)&Tph[m][sw] = ph;
      *(uint4*)&Tpl[m][sw] = pl;
    }
    // direct operand: float4 loads along K, b64 swizzled writes.
#pragma unroll
    for (int p = 0; p < 8; ++p) {
      const int row = (tid >> 4) + 16 * p;
      const float4 v = *(const float4*)&D[(long)row * ldD + k0 + (tid & 15) * 4];
      u16 h[4], l[4];
      splitbf(v.x, h[0], l[0]); splitbf(v.y, h[1], l[1]);
      splitbf(v.z, h[2], l[2]); splitbf(v.w, h[3], l[3]);
      uint2 ph, pl;
      ph.x = (u32)h[0] | ((u32)h[1] << 16); ph.y = (u32)h[2] | ((u32)h[3] << 16);
      pl.x = (u32)l[0] | ((u32)l[1] << 16); pl.y = (u32)l[2] | ((u32)l[3] << 16);
      const int s16 = ((tid & 15) >> 1) ^ (row & 7);
      const int off = s16 * 8 + (tid & 1) * 4;
      *(uint2*)&Dph[row][off] = ph;
      *(uint2*)&Dpl[row][off] = pl;
    }
  };

  f32x4 acc[4][4];
  const f32x4 vzero = {0.f, 0.f, 0.f, 0.f};
#pragma unroll
  for (int mi = 0; mi < 4; ++mi)
#pragma unroll
    for (int ni = 0; ni < 4; ++ni) acc[mi][ni] = vzero;

  const int wm = (wv >> 1) * 64, wn = (wv & 1) * 64;
  const int fr = ln & 15, fk = ln >> 4;

  const int nT = K / 64;
  stage(0);
  for (int t = 0; t < nT; ++t) {
    __syncthreads();
#pragma unroll
    for (int kk = 0; kk < 2; ++kk) {
      const int s = kk * 4 + fk;
      bf16x8 ah[4], al[4], bh[4], bl[4];
#pragma unroll
      for (int mi = 0; mi < 4; ++mi) {
        const int m = wm + mi * 16 + fr;
        const int o = (s ^ (m & 7)) * 8;
        ah[mi] = *(const bf16x8*)&Ah[m][o];
        al[mi] = *(const bf16x8*)&Al[m][o];
      }
#pragma unroll
      for (int ni = 0; ni < 4; ++ni) {
        const int n = wn + ni * 16 + fr;
        const int o = (s ^ (n & 7)) * 8;
        bh[ni] = *(const bf16x8*)&Bh[n][o];
        bl[ni] = *(const bf16x8*)&Bl[n][o];
      }
#pragma unroll
      for (int mi = 0; mi < 4; ++mi)
#pragma unroll
        for (int ni = 0; ni < 4; ++ni) {
          acc[mi][ni] = __builtin_amdgcn_mfma_f32_16x16x32_bf16(ah[mi], bh[ni], acc[mi][ni], 0, 0, 0);
          acc[mi][ni] = __builtin_amdgcn_mfma_f32_16x16x32_bf16(ah[mi], bl[ni], acc[mi][ni], 0, 0, 0);
          acc[mi][ni] = __builtin_amdgcn_mfma_f32_16x16x32_bf16(al[mi], bh[ni], acc[mi][ni], 0, 0, 0);
        }
    }
    __syncthreads();
    if (t + 1 < nT) stage((t + 1) * 64);
  }

  const int fq = ln >> 4;
#pragma unroll
  for (int mi = 0; mi < 4; ++mi)
#pragma unroll
    for (int ni = 0; ni < 4; ++ni) {
      const int col = n0 + wn + ni * 16 + fr;
      const float bc = BIAS_COL ? bias[col] : 0.f;
#pragma unroll
      for (int r = 0; r < 4; ++r) {
        const int row = m0 + wm + mi * 16 + fq * 4 + r;
        const float v = acc[mi][ni][r] + (BIAS_COL ? bc : bias[row]);
        u16 h, l;
        splitbf(v, h, l);
        Co_h[(long)row * ldc + col] = h;
        Co_l[(long)row * ldc + col] = l;
      }
    }
}

// ===========================================================================
// plane_gemm (G4): logits^T. A,B are pre-split bf16 planes, K-contiguous.
//   out2[j][i] = sum_c g_xT[j][c] * f_wT[i][c], fp32 output.
//   global_load_lds staging with pre-swizzled per-lane source (rule 21).
// ===========================================================================
__global__ __launch_bounds__(256, 2) void plane_gemm(
    const u16* __restrict__ Ahi, const u16* __restrict__ Alo,
    const u16* __restrict__ Bhi, const u16* __restrict__ Blo,
    int ldk, long sA, long sB,
    float* __restrict__ C, int ldcn, long sC, int K)
{
  __shared__ u16 lds[4][128][64];
  const int tid = threadIdx.x, ln = tid & 63, wv = tid >> 6;
  const int z = blockIdx.z;
  const int m0 = blockIdx.y * 128, n0 = blockIdx.x * 128;
  const u16* sp =
      (wv == 0) ? Ahi + (long)z * sA + (long)m0 * ldk :
      (wv == 1) ? Alo + (long)z * sA + (long)m0 * ldk :
      (wv == 2) ? Bhi + (long)z * sB + (long)n0 * ldk :
                  Blo + (long)z * sB + (long)n0 * ldk;
  float* Cz = C + (long)z * sC;

  auto stage = [&](int k0) {
    const u16* s0 = sp + k0 + (long)(ln >> 3) * ldk + ((ln & 7) ^ (ln >> 3)) * 8;
#pragma unroll
    for (int i = 0; i < 16; ++i)
      gload16(s0 + (long)(i * 8) * ldk, &lds[wv][i * 8][0]);
  };

  f32x4 acc[4][4];
  const f32x4 vzero = {0.f, 0.f, 0.f, 0.f};
#pragma unroll
  for (int mi = 0; mi < 4; ++mi)
#pragma unroll
    for (int ni = 0; ni < 4; ++ni) acc[mi][ni] = vzero;

  const int wm = (wv >> 1) * 64, wn = (wv & 1) * 64;
  const int fr = ln & 15, fk = ln >> 4;

  const int nT = K / 64;
  stage(0);
  for (int t = 0; t < nT; ++t) {
    asm volatile("s_waitcnt vmcnt(0)" ::: "memory");
    __syncthreads();
#pragma unroll
    for (int kk = 0; kk < 2; ++kk) {
      const int s = kk * 4 + fk;
      bf16x8 ah[4], al[4], bh[4], bl[4];
#pragma unroll
      for (int mi = 0; mi < 4; ++mi) {
        const int m = wm + mi * 16 + fr;
        const int o = (s ^ (m & 7)) * 8;
        ah[mi] = *(const bf16x8*)&lds[0][m][o];
        al[mi] = *(const bf16x8*)&lds[1][m][o];
      }
#pragma unroll
      for (int ni = 0; ni < 4; ++ni) {
        const int n = wn + ni * 16 + fr;
        const int o = (s ^ (n & 7)) * 8;
        bh[ni] = *(const bf16x8*)&lds[2][n][o];
        bl[ni] = *(const bf16x8*)&lds[3][n][o];
      }
#pragma unroll
      for (int mi = 0; mi < 4; ++mi)
#pragma unroll
        for (int ni = 0; ni < 4; ++ni) {
          acc[mi][ni] = __builtin_amdgcn_mfma_f32_16x16x32_bf16(ah[mi], bh[ni], acc[mi][ni], 0, 0, 0);
          acc[mi][ni] = __builtin_amdgcn_mfma_f32_16x16x32_bf16(ah[mi], bl[ni], acc[mi][ni], 0, 0, 0);
          acc[mi][ni] = __builtin_amdgcn_mfma_f32_16x16x32_bf16(al[mi], bh[ni], acc[mi][ni], 0, 0, 0);
        }
    }
    __syncthreads();
    if (t + 1 < nT) stage((t + 1) * 64);
  }

  const int fq = ln >> 4;
#pragma unroll
  for (int mi = 0; mi < 4; ++mi)
#pragma unroll
    for (int ni = 0; ni < 4; ++ni) {
      const int col = n0 + wn + ni * 16 + fr;
#pragma unroll
      for (int r = 0; r < 4; ++r) {
        const int row = m0 + wm + mi * 16 + fq * 4 + r;
        Cz[(long)row * ldcn + col] = acc[mi][ni][r];
      }
    }
}

// ===========================================================================
// softmax over contiguous rows of length 2304 (proven in round 1)
// ===========================================================================
__global__ __launch_bounds__(256) void softmax_rows_2304(float* __restrict__ P)
{
  float* p = P + (long)blockIdx.x * kN;
  const int tid = threadIdx.x;

  float v[9];
  float mx = -3.402823466e38f;
#pragma unroll
  for (int r = 0; r < 9; ++r) {
    v[r] = p[tid + 256 * r];
    mx = fmaxf(mx, v[r]);
  }
#pragma unroll
  for (int off = 32; off > 0; off >>= 1) mx = fmaxf(mx, __shfl_xor(mx, off, 64));

  __shared__ float red[8];
  const int wv = tid >> 6, lane = tid & 63;
  if (lane == 0) red[wv] = mx;
  __syncthreads();
  mx = fmaxf(fmaxf(red[0], red[1]), fmaxf(red[2], red[3]));

  float s = 0.f;
#pragma unroll
  for (int r = 0; r < 9; ++r) {
    v[r] = __expf(v[r] - mx);
    s += v[r];
  }
#pragma unroll
  for (int off = 32; off > 0; off >>= 1) s += __shfl_xor(s, off, 64);
  if (lane == 0) red[4 + wv] = s;
  __syncthreads();
  s = red[4] + red[5] + red[6] + red[7];

  const float inv = 1.f / s;
#pragma unroll
  for (int r = 0; r < 9; ++r) p[tid + 256 * r] = v[r] * inv;
}

// ===========================================================================
// g5_gemm: out1 = gamma * (h_x @ out2) + w
//   A = h planes (bf16 hi/lo, K-contiguous) via global_load_lds (swizzled src)
//   B = out2 fp32 [j][i], transpose+convert reg-staged (swizzled writes)
// ===========================================================================
__global__ __launch_bounds__(256, 2) void g5_gemm(
    const u16* __restrict__ Hhi, const u16* __restrict__ Hlo, long sH,
    const float* __restrict__ P, long sP,
    const float* __restrict__ Wres, long sW,
    const float* __restrict__ gammap,
    float* __restrict__ O, long sO)
{
  __shared__ u16 Ahx[2][128][64];
  __shared__ u16 Bhx[2][128][64];
  const int tid = threadIdx.x, ln = tid & 63, wv = tid >> 6;
  const int z = blockIdx.z, m0 = blockIdx.y * 128, n0 = blockIdx.x * 128;
  const u16* hp = ((wv & 1) ? Hlo : Hhi) + (long)z * sH + (long)m0 * kN;
  const float* Pz = P + (long)z * sP + n0;

  auto stageA = [&](int k0) {
    const int half = wv >> 1;
    const u16* s0 = hp + k0 + (long)(half * 64 + (ln >> 3)) * kN + ((ln & 7) ^ (ln >> 3)) * 8;
#pragma unroll
    for (int i = 0; i < 8; ++i)
      gload16(s0 + (long)(i * 8) * kN, &Ahx[wv & 1][half * 64 + i * 8][0]);
  };
  auto stageB = [&](int k0) {
#pragma unroll
    for (int s = 0; s < 4; ++s) {
      const int n = (tid & 63) + 64 * (s & 1);
      const int kr = (tid >> 6) + 4 * (s >> 1);
      const float* src = Pz + (long)(k0 + kr * 8) * kN + n;
      u16 h[8], l[8];
#pragma unroll
      for (int j = 0; j < 8; ++j) splitbf(src[(long)j * kN], h[j], l[j]);
      uint4 ph, pl;
      ph.x = (u32)h[0] | ((u32)h[1] << 16); ph.y = (u32)h[2] | ((u32)h[3] << 16);
      ph.z = (u32)h[4] | ((u32)h[5] << 16); ph.w = (u32)h[6] | ((u32)h[7] << 16);
      pl.x = (u32)l[0] | ((u32)l[1] << 16); pl.y = (u32)l[2] | ((u32)l[3] << 16);
      pl.z = (u32)l[4] | ((u32)l[5] << 16); pl.w = (u32)l[6] | ((u32)l[7] << 16);
      const int sw = (kr ^ (n & 7)) * 8;
      *(uint4*)&Bhx[0][n][sw] = ph;
      *(uint4*)&Bhx[1][n][sw] = pl;
    }
  };

  f32x4 acc[4][4];
  const f32x4 vzero = {0.f, 0.f, 0.f, 0.f};
#pragma unroll
  for (int mi = 0; mi < 4; ++mi)
#pragma unroll
    for (int ni = 0; ni < 4; ++ni) acc[mi][ni] = vzero;

  const int wm = (wv >> 1) * 64, wn = (wv & 1) * 64;
  const int fr = ln & 15, fk = ln >> 4;

  constexpr int nT = kN / 64;  // 36
  stageA(0);
  stageB(0);
  for (int t = 0; t < nT; ++t) {
    asm volatile("s_waitcnt vmcnt(0)" ::: "memory");
    __syncthreads();
#pragma unroll
    for (int kk = 0; kk < 2; ++kk) {
      const int s = kk * 4 + fk;
      bf16x8 ah[4], al[4], bh[4], bl[4];
#pragma unroll
      for (int mi = 0; mi < 4; ++mi) {
        const int m = wm + mi * 16 + fr;
        const int o = (s ^ (m & 7)) * 8;
        ah[mi] = *(const bf16x8*)&Ahx[0][m][o];
        al[mi] = *(const bf16x8*)&Ahx[1][m][o];
      }
#pragma unroll
      for (int ni = 0; ni < 4; ++ni) {
        const int n = wn + ni * 16 + fr;
        const int o = (s ^ (n & 7)) * 8;
        bh[ni] = *(const bf16x8*)&Bhx[0][n][o];
        bl[ni] = *(const bf16x8*)&Bhx[1][n][o];
      }
#pragma unroll
      for (int mi = 0; mi < 4; ++mi)
#pragma unroll
        for (int ni = 0; ni < 4; ++ni) {
          acc[mi][ni] = __builtin_amdgcn_mfma_f32_16x16x32_bf16(ah[mi], bh[ni], acc[mi][ni], 0, 0, 0);
          acc[mi][ni] = __builtin_amdgcn_mfma_f32_16x16x32_bf16(ah[mi], bl[ni], acc[mi][ni], 0, 0, 0);
          acc[mi][ni] = __builtin_amdgcn_mfma_f32_16x16x32_bf16(al[mi], bh[ni], acc[mi][ni], 0, 0, 0);
        }
    }
    __syncthreads();
    if (t + 1 < nT) {
      stageA((t + 1) * 64);
      stageB((t + 1) * 64);
    }
  }

  const float g = *gammap;
  const int fq = ln >> 4;
#pragma unroll
  for (int mi = 0; mi < 4; ++mi)
#pragma unroll
    for (int ni = 0; ni < 4; ++ni) {
      const int col = n0 + wn + ni * 16 + fr;
#pragma unroll
      for (int r = 0; r < 4; ++r) {
        const int row = m0 + wm + mi * 16 + fq * 4 + r;
        O[(long)z * sO + (long)row * kN + col] =
            g * acc[mi][ni][r] + Wres[(long)z * sW + (long)row * kN + col];
      }
    }
}

// ===========================================================================
extern "C" void kernel_launch(void* const* d_in, const int* in_sizes, int n_in,
                              void* d_out, int out_size, void* d_ws,
                              size_t ws_size, hipStream_t stream)
{
  const float* x  = (const float*)d_in[0];
  const float* w  = (const float*)d_in[1];
  const float* Wf = (const float*)d_in[2];
  const float* bf = (const float*)d_in[3];
  const float* Wg = (const float*)d_in[4];
  const float* bg = (const float*)d_in[5];
  const float* Wh = (const float*)d_in[6];
  const float* bh = (const float*)d_in[7];
  const float* gm = (const float*)d_in[8];

  // ws: split-bf16 planes, exactly 151 MB (same footprint as round 1)
  u16* f_hi = (u16*)d_ws;                          // f_wT [B][N][C2]
  u16* f_lo = f_hi + (long)kB * kN * kC2;
  u16* g_hi = f_lo + (long)kB * kN * kC2;          // g_xT [B][N][C2]
  u16* g_lo = g_hi + (long)kB * kN * kC2;
  u16* h_hi = g_lo + (long)kB * kN * kC2;          // h_x  [B][C][N]
  u16* h_lo = h_hi + (long)kB * kC * kN;

  float* out1 = (float*)d_out;                     // [B][C][N]
  float* out2 = out1 + (long)kB * kC * kN;         // [B][N][N] = attn_soft^T

  dim3 blk(256);

  // G1: f_wT[i][o] = sum_c w[c,i]*Wf[o,c] + bf[o]
  conv_gemm<true, true><<<dim3(kC2 / 128, kN / 128, kB), blk, 0, stream>>>(
      w, kN, (long)kC * kN, Wf, kC, 0, f_hi, f_lo, kC2, (long)kN * kC2, bf, kC);
  // G2: g_xT[j][o] = sum_c x[c,j]*Wg[o,c] + bg[o]
  conv_gemm<true, true><<<dim3(kC2 / 128, kN / 128, kB), blk, 0, stream>>>(
      x, kN, (long)kC * kN, Wg, kC, 0, g_hi, g_lo, kC2, (long)kN * kC2, bg, kC);
  // G3: h_x[o][n] = sum_c Wh[o,c]*x[c,n] + bh[o]
  conv_gemm<false, false><<<dim3(kN / 128, kC / 128, kB), blk, 0, stream>>>(
      x, kN, (long)kC * kN, Wh, kC, 0, h_hi, h_lo, kN, (long)kC * kN, bh, kC);
  // G4: out2[j][i] = sum_c g_xT[j][c]*f_wT[i][c]
  plane_gemm<<<dim3(kN / 128, kN / 128, kB), blk, 0, stream>>>(
      g_hi, g_lo, f_hi, f_lo, kC2, (long)kN * kC2, (long)kN * kC2,
      out2, kN, (long)kN * kN, kC2);
  // softmax over i (contiguous rows of out2)
  softmax_rows_2304<<<dim3(kB * kN), blk, 0, stream>>>(out2);
  // G5: out1[c][i] = gamma * sum_j h_x[c,j]*out2[j,i] + w[c,i]
  g5_gemm<<<dim3(kN / 128, kC / 128, kB), blk, 0, stream>>>(
      h_hi, h_lo, (long)kC * kN, out2, (long)kN * kN, w, (long)kC * kN, gm,
      out1, (long)kC * kN);
}